// Round 1
// 522.612 us; speedup vs baseline: 1.2166x; 1.2166x over previous
//
#include <hip/hip_runtime.h>
#include <hip/hip_bf16.h>
#include <cstdint>
#include <cstddef>

// Problem constants (from reference setup_inputs)
constexpr int BROWS = 4096;    // batch rows
constexpr int MREAL = 12893;   // prototypes
constexpr int MPAD  = 12928;   // 101*128, zero-padded rows in workspace
constexpr int KDIM  = 2048;
constexpr int NT    = KDIM / 64;   // 32 K-tiles of BK=64

typedef __attribute__((ext_vector_type(8))) short short8;   // 8 x bf16 (4 VGPRs)
typedef __attribute__((ext_vector_type(4))) float f32x4;    // MFMA accumulator

// Async global->LDS, 16B per lane. LDS dest = wave-uniform base + lane*16.
__device__ __forceinline__ void gld_lds16(const void* g, void* l) {
  __builtin_amdgcn_global_load_lds((__attribute__((address_space(1))) const void*)g,
                                   (__attribute__((address_space(3))) void*)l,
                                   16, 0, 0);
}

// ---------------------------------------------------------------------------
// Fused row-wise L2 normalize fp32 -> bf16 for BOTH x and p in one launch.
// Blocks [0, BROWS) -> x rows; [BROWS, BROWS+MPAD) -> p rows (pad rows zeroed).
// ---------------------------------------------------------------------------
__global__ void l2norm_fused(const float* __restrict__ x,
                             const float* __restrict__ p,
                             __hip_bfloat16* __restrict__ xn,
                             __hip_bfloat16* __restrict__ pn) {
  const int b = blockIdx.x;
  const int t = threadIdx.x;
  const float* irow;
  __hip_bfloat16* orow;
  if (b < BROWS) {
    irow = x + (size_t)b * KDIM;
    orow = xn + (size_t)b * KDIM;
  } else {
    const int row = b - BROWS;
    orow = pn + (size_t)row * KDIM;
    if (row >= MREAL) {   // uniform per block: zero-fill pad rows, no barrier used
      reinterpret_cast<float4*>(orow)[t] = make_float4(0.f, 0.f, 0.f, 0.f);
      return;
    }
    irow = p + (size_t)row * KDIM;
  }

  const float4* iv = reinterpret_cast<const float4*>(irow);
  float4 a = iv[t];        // elements 4t .. 4t+3
  float4 c = iv[t + 256];  // elements 1024+4t ..
  float ss = a.x*a.x + a.y*a.y + a.z*a.z + a.w*a.w
           + c.x*c.x + c.y*c.y + c.z*c.z + c.w*c.w;

  #pragma unroll
  for (int off = 32; off > 0; off >>= 1) ss += __shfl_down(ss, off);

  __shared__ float red[4];
  if ((t & 63) == 0) red[t >> 6] = ss;
  __syncthreads();
  float tot = red[0] + red[1] + red[2] + red[3];
  float inv = 1.0f / fmaxf(sqrtf(tot), 1e-12f);   // F.normalize semantics

  union { ushort4 u; __hip_bfloat16 h[4]; } o1, o2;
  o1.h[0] = __float2bfloat16(a.x * inv);
  o1.h[1] = __float2bfloat16(a.y * inv);
  o1.h[2] = __float2bfloat16(a.z * inv);
  o1.h[3] = __float2bfloat16(a.w * inv);
  o2.h[0] = __float2bfloat16(c.x * inv);
  o2.h[1] = __float2bfloat16(c.y * inv);
  o2.h[2] = __float2bfloat16(c.z * inv);
  o2.h[3] = __float2bfloat16(c.w * inv);
  reinterpret_cast<ushort4*>(orow)[t]       = o1.u;
  reinterpret_cast<ushort4*>(orow)[t + 256] = o2.u;
}

// ---------------------------------------------------------------------------
// C[b,m] = -|s| * sqrt(max(2 - 2*dot(xn[b], pn[m]), 0))
// 256x256 tile, BK=64, 8 waves (2M x 4N), 8-phase counted-vmcnt schedule
// (T2 xor-swizzle + T3/T4 pipelined staging + T5 setprio + T1 xcd swizzle).
// LDS: [2 bufs][A 256x64 | B 256x64] bf16 = 128 KiB, double-buffered K-tiles.
// Swizzle: LDS[row][slot p] holds global 16B-slot (p ^ (row&7))  (slots 0..7).
// Staged with linear LDS dest + inverse-swizzled GLOBAL source (rule #21).
// ---------------------------------------------------------------------------
__global__ __launch_bounds__(512, 2)
void gemm_dist(const __hip_bfloat16* __restrict__ A,
               const __hip_bfloat16* __restrict__ P,
               const float* __restrict__ scale,
               float* __restrict__ out) {
  __shared__ __hip_bfloat16 lds[65536];           // 128 KiB
  __hip_bfloat16* const sA = lds;                 // [2][256][64]
  __hip_bfloat16* const sB = lds + 32768;         // [2][256][64]

  const int t    = threadIdx.x;       // 0..511
  const int lane = t & 63;
  const int wv   = t >> 6;            // 0..7
  const int wm   = wv >> 2;           // 0..1 : wave row (128 rows each)
  const int wn   = wv & 3;            // 0..3 : wave col (64 cols each)

  // T1: bijective XCD swizzle. nwg = 816 = 8 * 102 (divisible -> simple form).
  const int bid = blockIdx.x;
  const int swz = (bid & 7) * 102 + (bid >> 3);
  const int bm0 = (swz / 51) * 256;   // M tile (16 tiles)
  const int bn0 = (swz % 51) * 256;   // N tile (51 tiles, covers 13056)

  // ---- staging map: thread covers LDS row srow(+64r), physical slot sp ----
  const int srow = t >> 3;            // 0..63
  const int sp   = t & 7;             // physical 16B slot
  const int ssl  = sp ^ (srow & 7);   // inverse-swizzled global slot
  const __hip_bfloat16* aSrc[4];
  const __hip_bfloat16* bSrc[4];
  int sOff[4];                        // LDS element offset (linear: == t*16 B)
  #pragma unroll
  for (int r = 0; r < 4; ++r) {
    aSrc[r] = A + (size_t)(bm0 + r*64 + srow) * KDIM + ssl*8;
    int br = bn0 + r*64 + srow;
    br = br < MPAD ? br : (MPAD - 1);          // clamp: rows >=12928 read zeros
    bSrc[r] = P + (size_t)br * KDIM + ssl*8;
    sOff[r] = (r*64 + srow)*64 + sp*8;
  }

  // ---- fragment map (A-layout: row = lane&15, k-slot = lane>>4; swizzled) ----
  const int l15 = lane & 15, hi = lane >> 4;
  const int pk0 = ( hi      ^ (lane & 7)) * 8;   // phys slot for kk=0 (elems)
  const int pk1 = ((hi + 4) ^ (lane & 7)) * 8;   // phys slot for kk=1
  const int aBase = (wm*128 + l15) * 64;
  const int bBase = (wn*64  + l15) * 64;

  f32x4 acc[8][4];
  #pragma unroll
  for (int i = 0; i < 8; ++i)
    #pragma unroll
    for (int j = 0; j < 4; ++j) acc[i][j] = f32x4{0.f, 0.f, 0.f, 0.f};

// One half-tile = 2 rounds of 64 rows = 2 x global_load_lds per thread.
#define STG_A(BUF, R, T) do { const int kt_ = ((T)*64) & (KDIM-1);            \
    gld_lds16(aSrc[(R)]   + kt_, sA + (BUF)*16384 + sOff[(R)]);               \
    gld_lds16(aSrc[(R)+1] + kt_, sA + (BUF)*16384 + sOff[(R)+1]); } while(0)
#define STG_B(BUF, R, T) do { const int kt_ = ((T)*64) & (KDIM-1);            \
    gld_lds16(bSrc[(R)]   + kt_, sB + (BUF)*16384 + sOff[(R)]);               \
    gld_lds16(bSrc[(R)+1] + kt_, sB + (BUF)*16384 + sOff[(R)+1]); } while(0)

  // Prologue: buf0 <- K-tile 0 (A+B, 8 loads); buf1.B <- K-tile 1 (4 loads).
  // vmcnt(4): K-tile 0 landed, B(K1) still in flight.
  STG_A(0, 0, 0); STG_A(0, 2, 0);
  STG_B(0, 0, 0); STG_B(0, 2, 0);
  STG_B(1, 0, 1); STG_B(1, 2, 1);
  asm volatile("s_waitcnt vmcnt(4)" ::: "memory");
  __builtin_amdgcn_s_barrier();

  short8 bfr[4][2];   // B fragments cached across the 4 quadrant phases

// Phase: {ds-read frags | issue half-tile} -> barrier -> lgkmcnt(0) ->
//        setprio(1) 16xMFMA setprio(0) -> [vmcnt(4)] -> barrier.
// Leading empty asm = compiler fence so no LDS read hoists above the
// previous trailing barrier (s_barrier builtin is IntrNoMem to LLVM).
#define PHASE(BUF, Q, READB, STG, VM) do {                                    \
    asm volatile("" ::: "memory");                                            \
    const __hip_bfloat16* sAb = sA + (BUF)*16384;                             \
    const __hip_bfloat16* sBb = sB + (BUF)*16384;                             \
    if (READB) {                                                              \
      _Pragma("unroll")                                                       \
      for (int j = 0; j < 4; ++j) {                                           \
        bfr[j][0] = *reinterpret_cast<const short8*>(sBb + bBase + j*1024 + pk0); \
        bfr[j][1] = *reinterpret_cast<const short8*>(sBb + bBase + j*1024 + pk1); \
      }                                                                       \
    }                                                                         \
    const short8 a00 = *reinterpret_cast<const short8*>(sAb + aBase + (Q)*2048 + pk0); \
    const short8 a01 = *reinterpret_cast<const short8*>(sAb + aBase + (Q)*2048 + pk1); \
    const short8 a10 = *reinterpret_cast<const short8*>(sAb + aBase + (Q)*2048 + 1024 + pk0); \
    const short8 a11 = *reinterpret_cast<const short8*>(sAb + aBase + (Q)*2048 + 1024 + pk1); \
    STG;                                                                      \
    __builtin_amdgcn_s_barrier();                                             \
    asm volatile("s_waitcnt lgkmcnt(0)" ::: "memory");                        \
    __builtin_amdgcn_s_setprio(1);                                            \
    _Pragma("unroll")                                                         \
    for (int j = 0; j < 4; ++j) {                                             \
      acc[2*(Q)  ][j] = __builtin_amdgcn_mfma_f32_16x16x32_bf16(a00, bfr[j][0], acc[2*(Q)  ][j], 0, 0, 0); \
      acc[2*(Q)  ][j] = __builtin_amdgcn_mfma_f32_16x16x32_bf16(a01, bfr[j][1], acc[2*(Q)  ][j], 0, 0, 0); \
      acc[2*(Q)+1][j] = __builtin_amdgcn_mfma_f32_16x16x32_bf16(a10, bfr[j][0], acc[2*(Q)+1][j], 0, 0, 0); \
      acc[2*(Q)+1][j] = __builtin_amdgcn_mfma_f32_16x16x32_bf16(a11, bfr[j][1], acc[2*(Q)+1][j], 0, 0, 0); \
    }                                                                         \
    __builtin_amdgcn_s_setprio(0);                                            \
    if (VM) asm volatile("s_waitcnt vmcnt(4)" ::: "memory");                  \
    __builtin_amdgcn_s_barrier();                                             \
  } while (0)

  // Issue schedule (iter i, T0=2i, T1=2i+1):
  //  ph1-2: A(T1)->buf1  (buf1.A dead since prev ph8)
  //  ph3-4: B(T0+2)->buf0 (buf0.B dead since ph1; vmcnt(4) at ph4 retires
  //                        B(T1)+A(T1) -> phases 5-8 may read buf1)
  //  ph5-6: A(T0+2)->buf0 (buf0.A dead since ph4)
  //  ph7-8: B(T1+2)->buf1 (buf1.B dead since ph5; vmcnt(4) at ph8 retires
  //                        B(T0+2)+A(T0+2) -> next iter reads buf0)
  // Over-end tiles (T>=32) wrap via &(KDIM-1): harmless loads, never consumed.
  for (int it = 0; it < NT/2; ++it) {
    const int T1 = 2*it + 1;
    PHASE(0, 0, true , STG_A(1, 0, T1),     false);
    PHASE(0, 1, false, STG_A(1, 2, T1),     false);
    PHASE(0, 2, false, STG_B(0, 0, (T1+1)), false);
    PHASE(0, 3, false, STG_B(0, 2, (T1+1)), true );
    PHASE(1, 0, true , STG_A(0, 0, (T1+1)), false);
    PHASE(1, 1, false, STG_A(0, 2, (T1+1)), false);
    PHASE(1, 2, false, STG_B(1, 0, (T1+2)), false);
    PHASE(1, 3, false, STG_B(1, 2, (T1+2)), true );
  }

  // Epilogue: C/D layout col = lane&15, row = (lane>>4)*4 + reg  [m89/m91]
  const float s = fabsf(scale[0]);
  const int colb = bn0 + wn*64 + l15;
  #pragma unroll
  for (int i = 0; i < 8; ++i) {
    const int rowb = bm0 + wm*128 + i*16 + hi*4;
    #pragma unroll
    for (int j = 0; j < 4; ++j) {
      const int col = colb + j*16;
      if (col < MREAL) {
        #pragma unroll
        for (int r = 0; r < 4; ++r) {
          float d2 = fmaxf(2.0f - 2.0f*acc[i][j][r], 0.0f);
          out[(size_t)(rowb + r)*MREAL + col] = -s * __builtin_sqrtf(d2);
        }
      }
    }
  }
  // Drain tail DMAs (4 in-flight LDS writes) before wave exit.
  asm volatile("s_waitcnt vmcnt(0)" ::: "memory");
}

#undef PHASE
#undef STG_A
#undef STG_B

// ---------------------------------------------------------------------------
extern "C" void kernel_launch(void* const* d_in, const int* in_sizes, int n_in,
                              void* d_out, int out_size, void* d_ws, size_t ws_size,
                              hipStream_t stream) {
  const float* x = (const float*)d_in[0];          // [4096, 2048] fp32
  const float* p = (const float*)d_in[1];          // [12893, 2048] fp32
  const float* s = (const float*)d_in[2];          // [1] fp32
  float* out = (float*)d_out;                      // [4096, 12893] fp32

  // Workspace: xn bf16 [4096][2048] then pn bf16 [12928][2048]  (~66.5 MB)
  __hip_bfloat16* xn = (__hip_bfloat16*)d_ws;
  __hip_bfloat16* pn = xn + (size_t)BROWS * KDIM;

  l2norm_fused<<<BROWS + MPAD, 256, 0, stream>>>(x, p, xn, pn);

  // 16 M-tiles x 51 N-tiles = 816 blocks (matches the XCD-swizzle constant).
  gemm_dist<<<816, 512, 0, stream>>>(xn, pn, s, out);
}